// Round 1
// baseline (50745.840 us; speedup 1.0000x reference)
//
#include <hip/hip_runtime.h>
#include <math.h>

#define S_TOK 4101
#define CDIM 1024

__device__ __forceinline__ float silu_f(float x) { return x / (1.f + expf(-x)); }
__device__ __forceinline__ float gelu_f(float x) { return 0.5f * x * (1.f + erff(x * 0.70710678118654752f)); }

// ---------------- t-freq embedding ----------------
__global__ void tfreq_kernel(const float* __restrict__ t, float* __restrict__ tf) {
    int i = threadIdx.x; // 0..255
    float tv = t[0];
    int f = i & 127;
    float fr = expf(-logf(10000.f) * (float)f / 128.f);
    float a = tv * fr;
    tf[i] = (i < 128) ? cosf(a) : sinf(a);
}

// out[j] = act(sum_i in[i]*W[i*ldw+j] + b[j])
__global__ void gemv_kernel(const float* __restrict__ in, const float* __restrict__ W, int ldw,
                            const float* __restrict__ bias, float* __restrict__ out,
                            int K, int N, int act) {
    int j = blockIdx.x * blockDim.x + threadIdx.x;
    if (j >= N) return;
    float acc = bias ? bias[j] : 0.f;
    for (int i = 0; i < K; ++i) acc = fmaf(in[i], W[(size_t)i * ldw + j], acc);
    if (act == 1) acc = silu_f(acc);
    out[j] = acc;
}

__global__ void silu_kernel(const float* __restrict__ in, float* __restrict__ out, int n) {
    int i = blockIdx.x * blockDim.x + threadIdx.x;
    if (i < n) out[i] = silu_f(in[i]);
}

// mod[b][j] = sum_i stemb[i]*ada_w[b][i][j] + ada_b[b][j]
__global__ void mod_kernel(const float* __restrict__ stemb, const float* __restrict__ ada_w,
                           const float* __restrict__ ada_b, float* __restrict__ mod) {
    int j = blockIdx.x * blockDim.x + threadIdx.x;
    if (j >= 4 * 6144) return;
    int b = j / 6144, c = j % 6144;
    const float* W = ada_w + (size_t)b * 1024 * 6144 + c;
    float acc = ada_b[j];
    for (int i = 0; i < 1024; ++i) acc = fmaf(stemb[i], W[(size_t)i * 6144], acc);
    mod[j] = acc;
}

// h[row][c]: rows 0..4 tokens, rows 5.. : x@in_w + in_b + pos_emb_3d
__global__ void embed_kernel(const float* __restrict__ x, const float* __restrict__ in_w,
                             const float* __restrict__ in_b, const float* __restrict__ pos_token,
                             const float* __restrict__ reg_token, float* __restrict__ h) {
    int id = blockIdx.x * 256 + threadIdx.x;
    if (id >= S_TOK * CDIM) return;
    int row = id >> 10, c = id & 1023;
    float v;
    if (row == 0) v = pos_token[c];
    else if (row < 5) v = reg_token[(row - 1) * 1024 + c];
    else {
        int l = row - 5;
        float acc = in_b[c];
#pragma unroll
        for (int ch = 0; ch < 8; ++ch) acc = fmaf(x[ch * 4096 + l], in_w[ch * 1024 + c], acc);
        float pe = 0.f;
        if (c < 1020) {
            int coordIdx = c / 340, r2 = c % 340;
            int coord;
            if (coordIdx == 0) coord = l >> 8;
            else if (coordIdx == 1) coord = (l >> 4) & 15;
            else coord = l & 15;
            int f = (r2 < 170) ? r2 : r2 - 170;
            float fr = expf(-logf(10000.f) * (float)f / 170.f);
            float a = (float)coord * fr;
            pe = (r2 < 170) ? sinf(a) : cosf(a);
        }
        v = acc + pe;
    }
    h[id] = v;
}

// ---------------- LayerNorm: mode 0 plain, 1: y=t*(1+w[c])+b[c], 2: y=t*w[c]+b[c]
__global__ __launch_bounds__(256) void ln_kernel(const float* __restrict__ X, float* __restrict__ Y,
                                                 const float* __restrict__ w, const float* __restrict__ b,
                                                 int mode) {
    int row = blockIdx.x;
    const float* x = X + (size_t)row * CDIM;
    float4 v = ((const float4*)x)[threadIdx.x];
    float s = v.x + v.y + v.z + v.w;
    float ss = v.x * v.x + v.y * v.y + v.z * v.z + v.w * v.w;
#pragma unroll
    for (int o = 32; o > 0; o >>= 1) { s += __shfl_xor(s, o); ss += __shfl_xor(ss, o); }
    __shared__ float sa[4], sb[4];
    int wv = threadIdx.x >> 6;
    if ((threadIdx.x & 63) == 0) { sa[wv] = s; sb[wv] = ss; }
    __syncthreads();
    s = sa[0] + sa[1] + sa[2] + sa[3];
    ss = sb[0] + sb[1] + sb[2] + sb[3];
    float mean = s * (1.f / 1024.f);
    float var = ss * (1.f / 1024.f) - mean * mean;
    float r = rsqrtf(var + 1e-6f);
    int c = threadIdx.x << 2;
    float t0 = (v.x - mean) * r, t1 = (v.y - mean) * r, t2 = (v.z - mean) * r, t3 = (v.w - mean) * r;
    float4 o4;
    if (mode == 0) { o4.x = t0; o4.y = t1; o4.z = t2; o4.w = t3; }
    else if (mode == 1) {
        o4.x = t0 * (1.f + w[c]) + b[c];
        o4.y = t1 * (1.f + w[c + 1]) + b[c + 1];
        o4.z = t2 * (1.f + w[c + 2]) + b[c + 2];
        o4.w = t3 * (1.f + w[c + 3]) + b[c + 3];
    } else {
        o4.x = t0 * w[c] + b[c];
        o4.y = t1 * w[c + 1] + b[c + 1];
        o4.z = t2 * w[c + 2] + b[c + 2];
        o4.w = t3 * w[c + 3] + b[c + 3];
    }
    ((float4*)(Y + (size_t)row * CDIM))[threadIdx.x] = o4;
}

// ---------------- SGEMM: C[M,N] = A[M,K]@B[K,N] + bias, optional gelu ----------------
#define BM 64
#define BN 64
#define BK 16
__global__ __launch_bounds__(256) void sgemm_kernel(const float* __restrict__ A, int lda,
                                                    const float* __restrict__ B, int ldb,
                                                    float* __restrict__ Cc, int ldc,
                                                    int M, int N, int K,
                                                    const float* __restrict__ bias, int act) {
    __shared__ float As[BK][BM];
    __shared__ float Bs[BK][BN];
    int t = threadIdx.x;
    int tx = t & 15;   // N dir
    int ty = t >> 4;   // M dir
    int m0 = blockIdx.y * BM;
    int n0 = blockIdx.x * BN;
    float acc[4][4] = {};
    int arow = t >> 2;
    int acol = (t & 3) << 2;
    int brow = t >> 4;
    int bcol = (t & 15) << 2;
    const float* Aptr = A + (size_t)(m0 + arow) * lda + acol;
    bool avalid = (m0 + arow) < M;
    const float* Bptr = B + (size_t)brow * ldb + n0 + bcol;
    for (int k0 = 0; k0 < K; k0 += BK) {
        float4 a4, b4;
        if (avalid) a4 = *(const float4*)(Aptr + k0);
        else a4 = make_float4(0.f, 0.f, 0.f, 0.f);
        b4 = *(const float4*)(Bptr + (size_t)k0 * ldb);
        As[acol + 0][arow] = a4.x;
        As[acol + 1][arow] = a4.y;
        As[acol + 2][arow] = a4.z;
        As[acol + 3][arow] = a4.w;
        *(float4*)&Bs[brow][bcol] = b4;
        __syncthreads();
#pragma unroll
        for (int kk = 0; kk < BK; ++kk) {
            float4 a = *(const float4*)&As[kk][ty << 2];
            float4 b = *(const float4*)&Bs[kk][tx << 2];
            float av[4] = {a.x, a.y, a.z, a.w};
            float bv[4] = {b.x, b.y, b.z, b.w};
#pragma unroll
            for (int r = 0; r < 4; ++r)
#pragma unroll
                for (int c = 0; c < 4; ++c) acc[r][c] = fmaf(av[r], bv[c], acc[r][c]);
        }
        __syncthreads();
    }
#pragma unroll
    for (int r = 0; r < 4; ++r) {
        int row = m0 + (ty << 2) + r;
        if (row < M) {
            int col = n0 + (tx << 2);
            float4 o;
            o.x = acc[r][0] + (bias ? bias[col + 0] : 0.f);
            o.y = acc[r][1] + (bias ? bias[col + 1] : 0.f);
            o.z = acc[r][2] + (bias ? bias[col + 2] : 0.f);
            o.w = acc[r][3] + (bias ? bias[col + 3] : 0.f);
            if (act == 1) { o.x = gelu_f(o.x); o.y = gelu_f(o.y); o.z = gelu_f(o.z); o.w = gelu_f(o.w); }
            *(float4*)(Cc + (size_t)row * ldc + col) = o;
        }
    }
}

// ---------------- RMS-norm * gamma on q,k slices of qkv buffer ----------------
__global__ void rms_kernel(float* __restrict__ qkv, const float* __restrict__ qg,
                           const float* __restrict__ kg, int S) {
    int gid = blockIdx.x * blockDim.x + threadIdx.x;
    int wid = gid >> 6;
    int lane = gid & 63;
    int total = 2 * S * 16;
    if (wid >= total) return;
    int isK = (wid >= S * 16) ? 1 : 0;
    int rem = isK ? (wid - S * 16) : wid;
    int s = rem / 16, hh = rem % 16;
    float* p = qkv + (size_t)s * 3072 + isK * 1024 + hh * 64 + lane;
    float v = *p;
    float sq = v * v;
#pragma unroll
    for (int o = 32; o > 0; o >>= 1) sq += __shfl_xor(sq, o);
    float r = rsqrtf(sq * (1.f / 64.f) + 1e-6f);
    const float* g = isK ? kg : qg;
    *p = v * r * g[hh * 64 + lane];
}

// ---------------- Flash attention (fp32, online softmax) ----------------
// Block: 256 threads = 32 queries x 8 key/dim slots. Tiles: TQ=32, TK=64. HD=64, NH=16.
__global__ __launch_bounds__(256) void attn_kernel(const float* __restrict__ Q, int qs,
                                                   const float* __restrict__ K, int ks,
                                                   const float* __restrict__ V, int vs,
                                                   float* __restrict__ O, int os,
                                                   int Sq, int Sk) {
    __shared__ float sQ[32][65];
    __shared__ float sK[64][64];
    __shared__ float sV[64][64];
    __shared__ float sP[32][65];
    __shared__ float sM[32], sL[32], sA[32];
    int hh = blockIdx.y;
    int q0 = blockIdx.x * 32;
    int t = threadIdx.x;
    int qi = t & 31, slot = t >> 5;
    const float* Qh = Q + hh * 64;
    const float* Kh = K + hh * 64;
    const float* Vh = V + hh * 64;
    // stage Q tile
    {
        int row = t >> 3;
        int col = (t & 7) << 3;
        int gr = q0 + row;
        if (gr < Sq) {
            const float* p = Qh + (size_t)gr * qs + col;
#pragma unroll
            for (int j = 0; j < 8; ++j) sQ[row][col + j] = p[j];
        } else {
#pragma unroll
            for (int j = 0; j < 8; ++j) sQ[row][col + j] = 0.f;
        }
    }
    if (t < 32) { sM[t] = -1e30f; sL[t] = 0.f; }
    __syncthreads();
    float qreg[64];
#pragma unroll
    for (int d = 0; d < 64; ++d) qreg[d] = sQ[qi][d];
    float oacc[8] = {0.f, 0.f, 0.f, 0.f, 0.f, 0.f, 0.f, 0.f};
    int d0 = slot << 3;
    for (int k0 = 0; k0 < Sk; k0 += 64) {
        __syncthreads();  // protect sK/sV/sP from previous iteration readers
#pragma unroll
        for (int i = 0; i < 4; ++i) {
            int e = i * 1024 + (t << 2);
            int row = e >> 6, col = e & 63;
            int gr = k0 + row;
            float4 k4, v4;
            if (gr < Sk) {
                k4 = *(const float4*)(Kh + (size_t)gr * ks + col);
                v4 = *(const float4*)(Vh + (size_t)gr * vs + col);
            } else {
                k4 = make_float4(0.f, 0.f, 0.f, 0.f);
                v4 = k4;
            }
            *(float4*)&sK[row][col] = k4;
            *(float4*)&sV[row][col] = v4;
        }
        __syncthreads();
        // scores for keys slot*8 .. slot*8+7
#pragma unroll
        for (int j = 0; j < 8; ++j) {
            int key = (slot << 3) + j;
            float acc = 0.f;
#pragma unroll
            for (int d = 0; d < 64; ++d) acc = fmaf(qreg[d], sK[key][d], acc);
            sP[qi][key] = acc * 0.125f;
        }
        __syncthreads();
        // online softmax (serial per query, threads 0..31)
        if (t < 32) {
            int kvalid = Sk - k0;
            if (kvalid > 64) kvalid = 64;
            float m = sM[t];
            for (int key = 0; key < kvalid; ++key) m = fmaxf(m, sP[t][key]);
            float alpha = expf(sM[t] - m);
            float lsum = 0.f;
            for (int key = 0; key < 64; ++key) {
                float p = (key < kvalid) ? expf(sP[t][key] - m) : 0.f;
                sP[t][key] = p;
                lsum += p;
            }
            sA[t] = alpha;
            sL[t] = sL[t] * alpha + lsum;
            sM[t] = m;
        }
        __syncthreads();
        float al = sA[qi];
#pragma unroll
        for (int j = 0; j < 8; ++j) oacc[j] *= al;
        for (int key = 0; key < 64; ++key) {
            float p = sP[qi][key];
#pragma unroll
            for (int j = 0; j < 8; ++j) oacc[j] = fmaf(p, sV[key][d0 + j], oacc[j]);
        }
    }
    int qrow = q0 + qi;
    if (qrow < Sq) {
        float inv = 1.f / sL[qi];
        float* op = O + (size_t)qrow * os + hh * 64 + d0;
#pragma unroll
        for (int j = 0; j < 8; ++j) op[j] = oacc[j] * inv;
    }
}

// h += (g ? g[c]* : 1*) p   (float4 over S*1024)
__global__ void resid_kernel(float* __restrict__ h, const float* __restrict__ p,
                             const float* __restrict__ g, int n4) {
    int i = blockIdx.x * 256 + threadIdx.x;
    if (i >= n4) return;
    float4 hv = ((float4*)h)[i];
    float4 pv = ((const float4*)p)[i];
    if (g) {
        int c = (i & 255) << 2;
        hv.x += g[c] * pv.x;
        hv.y += g[c + 1] * pv.y;
        hv.z += g[c + 2] * pv.z;
        hv.w += g[c + 3] * pv.w;
    } else {
        hv.x += pv.x; hv.y += pv.y; hv.z += pv.z; hv.w += pv.w;
    }
    ((float4*)h)[i] = hv;
}

// out[c][l] = hn[5+l] . out_w[:,c] + out_b[c]
__global__ void out_kernel(const float* __restrict__ hn, const float* __restrict__ out_w,
                           const float* __restrict__ out_b, float* __restrict__ out) {
    int id = blockIdx.x * 256 + threadIdx.x;
    if (id >= 4096 * 8) return;
    int l = id >> 3, c = id & 7;
    const float* row = hn + (size_t)(5 + l) * CDIM;
    float acc = out_b[c];
    for (int k = 0; k < 1024; ++k) acc = fmaf(row[k], out_w[k * 8 + c], acc);
    out[c * 4096 + l] = acc;
}

extern "C" void kernel_launch(void* const* d_in, const int* in_sizes, int n_in,
                              void* d_out, int out_size, void* d_ws, size_t ws_size,
                              hipStream_t stream) {
    const float* x        = (const float*)d_in[0];
    const float* t        = (const float*)d_in[1];
    const float* cond     = (const float*)d_in[2];
    const float* t_w1     = (const float*)d_in[3];
    const float* t_b1     = (const float*)d_in[4];
    const float* t_w2     = (const float*)d_in[5];
    const float* t_b2     = (const float*)d_in[6];
    const float* in_w     = (const float*)d_in[7];
    const float* in_b     = (const float*)d_in[8];
    const float* pos_tok  = (const float*)d_in[9];
    const float* reg_tok  = (const float*)d_in[10];
    const float* ada_w    = (const float*)d_in[11];
    const float* ada_b    = (const float*)d_in[12];
    const float* qkv_w    = (const float*)d_in[13];
    const float* qkv_b    = (const float*)d_in[14];
    const float* q_gamma  = (const float*)d_in[15];
    const float* k_gamma  = (const float*)d_in[16];
    const float* attn_ow  = (const float*)d_in[17];
    const float* attn_ob  = (const float*)d_in[18];
    const float* n2_w     = (const float*)d_in[19];
    const float* n2_b     = (const float*)d_in[20];
    const float* cq_w     = (const float*)d_in[21];
    const float* cq_b     = (const float*)d_in[22];
    const float* ckv_w    = (const float*)d_in[23];
    const float* ckv_b    = (const float*)d_in[24];
    const float* co_w     = (const float*)d_in[25];
    const float* co_b     = (const float*)d_in[26];
    const float* mlp_w1   = (const float*)d_in[27];
    const float* mlp_b1   = (const float*)d_in[28];
    const float* mlp_w2   = (const float*)d_in[29];
    const float* mlp_b2   = (const float*)d_in[30];
    const float* out_w    = (const float*)d_in[31];
    const float* out_b    = (const float*)d_in[32];

    const int S = S_TOK;
    float* ws = (float*)d_ws;
    float* h    = ws;
    float* hn   = h + (size_t)S * 1024;
    float* D    = hn + (size_t)S * 1024;        // S*4096: qkv / q+kv / ff1
    float* E    = D + (size_t)S * 4096;         // S*1024: sdpa out
    float* F    = E + (size_t)S * 1024;         // S*1024: proj out
    float* tf   = F + (size_t)S * 1024;
    float* s1   = tf + 256;
    float* temb = s1 + 1024;
    float* stemb = temb + 1024;
    float* mod  = stemb + 1024;                 // 4*6144

    // temb / adaLN modulation chain
    tfreq_kernel<<<1, 256, 0, stream>>>(t, tf);
    gemv_kernel<<<4, 256, 0, stream>>>(tf, t_w1, 1024, t_b1, s1, 256, 1024, 1);
    gemv_kernel<<<4, 256, 0, stream>>>(s1, t_w2, 1024, t_b2, temb, 1024, 1024, 0);
    silu_kernel<<<4, 256, 0, stream>>>(temb, stemb, 1024);
    mod_kernel<<<96, 256, 0, stream>>>(stemb, ada_w, ada_b, mod);

    // input embed + pos emb + tokens
    embed_kernel<<<(S * 1024 + 255) / 256, 256, 0, stream>>>(x, in_w, in_b, pos_tok, reg_tok, h);

    int gy = (S + 63) / 64;     // 65
    int aqx = (S + 31) / 32;    // 129
    for (int i = 0; i < 4; ++i) {
        const float* modb = mod + i * 6144;
        // hn = ln(h)*(1+sc1)+sh1
        ln_kernel<<<S, 256, 0, stream>>>(h, hn, modb + 1024, modb + 0, 1);
        // qkv = hn @ qkv_w + qkv_b
        sgemm_kernel<<<dim3(3072 / 64, gy), 256, 0, stream>>>(hn, 1024, qkv_w + (size_t)i * 1024 * 3072, 3072,
                                                              D, 3072, S, 3072, 1024, qkv_b + i * 3072, 0);
        // rms+gamma on q,k
        rms_kernel<<<(2 * S * 16 * 64 + 255) / 256, 256, 0, stream>>>(D, q_gamma + i * 1024, k_gamma + i * 1024, S);
        // self attention
        attn_kernel<<<dim3(aqx, 16), 256, 0, stream>>>(D, 3072, D + 1024, 3072, D + 2048, 3072, E, 1024, S, S);
        // o-proj
        sgemm_kernel<<<dim3(16, gy), 256, 0, stream>>>(E, 1024, attn_ow + (size_t)i * 1024 * 1024, 1024,
                                                       F, 1024, S, 1024, 1024, attn_ob + i * 1024, 0);
        // h += g1 * o
        resid_kernel<<<S, 256, 0, stream>>>(h, F, modb + 2 * 1024, S * 256);

        // hn = ln(h, n2_w, n2_b)
        ln_kernel<<<S, 256, 0, stream>>>(h, hn, n2_w + i * 1024, n2_b + i * 1024, 2);
        // q = hn @ cq_w
        sgemm_kernel<<<dim3(16, gy), 256, 0, stream>>>(hn, 1024, cq_w + (size_t)i * 1024 * 1024, 1024,
                                                       D, 1024, S, 1024, 1024, cq_b + i * 1024, 0);
        // kv = cond @ ckv_w
        float* kvD = D + (size_t)S * 1024;
        sgemm_kernel<<<dim3(32, 16), 256, 0, stream>>>(cond, 1024, ckv_w + (size_t)i * 1024 * 2048, 2048,
                                                       kvD, 2048, 1024, 2048, 1024, ckv_b + i * 2048, 0);
        // cross attention
        attn_kernel<<<dim3(aqx, 16), 256, 0, stream>>>(D, 1024, kvD, 2048, kvD + 1024, 2048, E, 1024, S, 1024);
        // co proj
        sgemm_kernel<<<dim3(16, gy), 256, 0, stream>>>(E, 1024, co_w + (size_t)i * 1024 * 1024, 1024,
                                                       F, 1024, S, 1024, 1024, co_b + i * 1024, 0);
        // h += o
        resid_kernel<<<S, 256, 0, stream>>>(h, F, nullptr, S * 256);

        // hn = ln(h)*(1+sc2)+sh2
        ln_kernel<<<S, 256, 0, stream>>>(h, hn, modb + 4 * 1024, modb + 3 * 1024, 1);
        // ff1 = gelu(hn @ mlp_w1 + b1)
        sgemm_kernel<<<dim3(64, gy), 256, 0, stream>>>(hn, 1024, mlp_w1 + (size_t)i * 1024 * 4096, 4096,
                                                       D, 4096, S, 4096, 1024, mlp_b1 + i * 4096, 1);
        // ff2 = ff1 @ mlp_w2 + b2
        sgemm_kernel<<<dim3(16, gy), 256, 0, stream>>>(D, 4096, mlp_w2 + (size_t)i * 4096 * 1024, 1024,
                                                       F, 1024, S, 1024, 4096, mlp_b2 + i * 1024, 0);
        // h += g2 * ff
        resid_kernel<<<S, 256, 0, stream>>>(h, F, modb + 5 * 1024, S * 256);
    }
    // final LN + out proj + transpose
    ln_kernel<<<S, 256, 0, stream>>>(h, hn, nullptr, nullptr, 0);
    out_kernel<<<128, 256, 0, stream>>>(hn, out_w, out_b, (float*)d_out);
}

// Round 2
// 20115.746 us; speedup vs baseline: 2.5227x; 2.5227x over previous
//
#include <hip/hip_runtime.h>
#include <math.h>

#define S_TOK 4101
#define CDIM 1024

__device__ __forceinline__ float silu_f(float x) { return x / (1.f + expf(-x)); }
__device__ __forceinline__ float gelu_f(float x) { return 0.5f * x * (1.f + erff(x * 0.70710678118654752f)); }

// ---------------- t-freq embedding ----------------
__global__ void tfreq_kernel(const float* __restrict__ t, float* __restrict__ tf) {
    int i = threadIdx.x; // 0..255
    float tv = t[0];
    int f = i & 127;
    float fr = expf(-logf(10000.f) * (float)f / 128.f);
    float a = tv * fr;
    tf[i] = (i < 128) ? cosf(a) : sinf(a);
}

// out[j] = act(sum_i in[i]*W[i*ldw+j] + b[j])
__global__ void gemv_kernel(const float* __restrict__ in, const float* __restrict__ W, int ldw,
                            const float* __restrict__ bias, float* __restrict__ out,
                            int K, int N, int act) {
    int j = blockIdx.x * blockDim.x + threadIdx.x;
    if (j >= N) return;
    float acc = bias ? bias[j] : 0.f;
    for (int i = 0; i < K; ++i) acc = fmaf(in[i], W[(size_t)i * ldw + j], acc);
    if (act == 1) acc = silu_f(acc);
    out[j] = acc;
}

__global__ void silu_kernel(const float* __restrict__ in, float* __restrict__ out, int n) {
    int i = blockIdx.x * blockDim.x + threadIdx.x;
    if (i < n) out[i] = silu_f(in[i]);
}

// mod[b][j] = sum_i stemb[i]*ada_w[b][i][j] + ada_b[b][j]
__global__ void mod_kernel(const float* __restrict__ stemb, const float* __restrict__ ada_w,
                           const float* __restrict__ ada_b, float* __restrict__ mod) {
    int j = blockIdx.x * blockDim.x + threadIdx.x;
    if (j >= 4 * 6144) return;
    int b = j / 6144, c = j % 6144;
    const float* W = ada_w + (size_t)b * 1024 * 6144 + c;
    float acc = ada_b[j];
    for (int i = 0; i < 1024; ++i) acc = fmaf(stemb[i], W[(size_t)i * 6144], acc);
    mod[j] = acc;
}

// h[row][c]: rows 0..4 tokens, rows 5.. : x@in_w + in_b + pos_emb_3d
__global__ void embed_kernel(const float* __restrict__ x, const float* __restrict__ in_w,
                             const float* __restrict__ in_b, const float* __restrict__ pos_token,
                             const float* __restrict__ reg_token, float* __restrict__ h) {
    int id = blockIdx.x * 256 + threadIdx.x;
    if (id >= S_TOK * CDIM) return;
    int row = id >> 10, c = id & 1023;
    float v;
    if (row == 0) v = pos_token[c];
    else if (row < 5) v = reg_token[(row - 1) * 1024 + c];
    else {
        int l = row - 5;
        float acc = in_b[c];
#pragma unroll
        for (int ch = 0; ch < 8; ++ch) acc = fmaf(x[ch * 4096 + l], in_w[ch * 1024 + c], acc);
        float pe = 0.f;
        if (c < 1020) {
            int coordIdx = c / 340, r2 = c % 340;
            int coord;
            if (coordIdx == 0) coord = l >> 8;
            else if (coordIdx == 1) coord = (l >> 4) & 15;
            else coord = l & 15;
            int f = (r2 < 170) ? r2 : r2 - 170;
            float fr = expf(-logf(10000.f) * (float)f / 170.f);
            float a = (float)coord * fr;
            pe = (r2 < 170) ? sinf(a) : cosf(a);
        }
        v = acc + pe;
    }
    h[id] = v;
}

// ---------------- LayerNorm: mode 0 plain, 1: y=t*(1+w[c])+b[c], 2: y=t*w[c]+b[c]
__global__ __launch_bounds__(256) void ln_kernel(const float* __restrict__ X, float* __restrict__ Y,
                                                 const float* __restrict__ w, const float* __restrict__ b,
                                                 int mode) {
    int row = blockIdx.x;
    const float* x = X + (size_t)row * CDIM;
    float4 v = ((const float4*)x)[threadIdx.x];
    float s = v.x + v.y + v.z + v.w;
    float ss = v.x * v.x + v.y * v.y + v.z * v.z + v.w * v.w;
#pragma unroll
    for (int o = 32; o > 0; o >>= 1) { s += __shfl_xor(s, o); ss += __shfl_xor(ss, o); }
    __shared__ float sa[4], sb[4];
    int wv = threadIdx.x >> 6;
    if ((threadIdx.x & 63) == 0) { sa[wv] = s; sb[wv] = ss; }
    __syncthreads();
    s = sa[0] + sa[1] + sa[2] + sa[3];
    ss = sb[0] + sb[1] + sb[2] + sb[3];
    float mean = s * (1.f / 1024.f);
    float var = ss * (1.f / 1024.f) - mean * mean;
    float r = rsqrtf(var + 1e-6f);
    int c = threadIdx.x << 2;
    float t0 = (v.x - mean) * r, t1 = (v.y - mean) * r, t2 = (v.z - mean) * r, t3 = (v.w - mean) * r;
    float4 o4;
    if (mode == 0) { o4.x = t0; o4.y = t1; o4.z = t2; o4.w = t3; }
    else if (mode == 1) {
        o4.x = t0 * (1.f + w[c]) + b[c];
        o4.y = t1 * (1.f + w[c + 1]) + b[c + 1];
        o4.z = t2 * (1.f + w[c + 2]) + b[c + 2];
        o4.w = t3 * (1.f + w[c + 3]) + b[c + 3];
    } else {
        o4.x = t0 * w[c] + b[c];
        o4.y = t1 * w[c + 1] + b[c + 1];
        o4.z = t2 * w[c + 2] + b[c + 2];
        o4.w = t3 * w[c + 3] + b[c + 3];
    }
    ((float4*)(Y + (size_t)row * CDIM))[threadIdx.x] = o4;
}

// ---------------- SGEMM: C[M,N] = A[M,K]@B[K,N] + bias, optional gelu ----------------
#define BM 64
#define BN 64
#define BK 16
__global__ __launch_bounds__(256) void sgemm_kernel(const float* __restrict__ A, int lda,
                                                    const float* __restrict__ B, int ldb,
                                                    float* __restrict__ Cc, int ldc,
                                                    int M, int N, int K,
                                                    const float* __restrict__ bias, int act) {
    __shared__ float As[BK][BM];
    __shared__ float Bs[BK][BN];
    int t = threadIdx.x;
    int tx = t & 15;   // N dir
    int ty = t >> 4;   // M dir
    int m0 = blockIdx.y * BM;
    int n0 = blockIdx.x * BN;
    float acc[4][4] = {};
    int arow = t >> 2;
    int acol = (t & 3) << 2;
    int brow = t >> 4;
    int bcol = (t & 15) << 2;
    const float* Aptr = A + (size_t)(m0 + arow) * lda + acol;
    bool avalid = (m0 + arow) < M;
    const float* Bptr = B + (size_t)brow * ldb + n0 + bcol;
    for (int k0 = 0; k0 < K; k0 += BK) {
        float4 a4, b4;
        if (avalid) a4 = *(const float4*)(Aptr + k0);
        else a4 = make_float4(0.f, 0.f, 0.f, 0.f);
        b4 = *(const float4*)(Bptr + (size_t)k0 * ldb);
        As[acol + 0][arow] = a4.x;
        As[acol + 1][arow] = a4.y;
        As[acol + 2][arow] = a4.z;
        As[acol + 3][arow] = a4.w;
        *(float4*)&Bs[brow][bcol] = b4;
        __syncthreads();
#pragma unroll
        for (int kk = 0; kk < BK; ++kk) {
            float4 a = *(const float4*)&As[kk][ty << 2];
            float4 b = *(const float4*)&Bs[kk][tx << 2];
            float av[4] = {a.x, a.y, a.z, a.w};
            float bv[4] = {b.x, b.y, b.z, b.w};
#pragma unroll
            for (int r = 0; r < 4; ++r)
#pragma unroll
                for (int c = 0; c < 4; ++c) acc[r][c] = fmaf(av[r], bv[c], acc[r][c]);
        }
        __syncthreads();
    }
#pragma unroll
    for (int r = 0; r < 4; ++r) {
        int row = m0 + (ty << 2) + r;
        if (row < M) {
            int col = n0 + (tx << 2);
            float4 o;
            o.x = acc[r][0] + (bias ? bias[col + 0] : 0.f);
            o.y = acc[r][1] + (bias ? bias[col + 1] : 0.f);
            o.z = acc[r][2] + (bias ? bias[col + 2] : 0.f);
            o.w = acc[r][3] + (bias ? bias[col + 3] : 0.f);
            if (act == 1) { o.x = gelu_f(o.x); o.y = gelu_f(o.y); o.z = gelu_f(o.z); o.w = gelu_f(o.w); }
            *(float4*)(Cc + (size_t)row * ldc + col) = o;
        }
    }
}

// ---------------- RMS-norm * gamma on q,k slices of qkv buffer ----------------
__global__ void rms_kernel(float* __restrict__ qkv, const float* __restrict__ qg,
                           const float* __restrict__ kg, int S) {
    int gid = blockIdx.x * blockDim.x + threadIdx.x;
    int wid = gid >> 6;
    int lane = gid & 63;
    int total = 2 * S * 16;
    if (wid >= total) return;
    int isK = (wid >= S * 16) ? 1 : 0;
    int rem = isK ? (wid - S * 16) : wid;
    int s = rem / 16, hh = rem % 16;
    float* p = qkv + (size_t)s * 3072 + isK * 1024 + hh * 64 + lane;
    float v = *p;
    float sq = v * v;
#pragma unroll
    for (int o = 32; o > 0; o >>= 1) sq += __shfl_xor(sq, o);
    float r = rsqrtf(sq * (1.f / 64.f) + 1e-6f);
    const float* g = isK ? kg : qg;
    *p = v * r * g[hh * 64 + lane];
}

// ---------------- Flash attention (fp32, parallel online softmax) ----------------
// Block: 256 threads = 16x16; 64 queries x 64 keys per tile; 4x4 microtile/thread.
// Row state (m,l) replicated across the 16 tx-lanes of each row; reductions via
// 16-lane shuffle butterflies. HD=64, NH=16.
__global__ __launch_bounds__(256) void attn_kernel(const float* __restrict__ Q, int qs,
                                                   const float* __restrict__ K, int ks,
                                                   const float* __restrict__ V, int vs,
                                                   float* __restrict__ O, int os,
                                                   int Sq, int Sk) {
    __shared__ float sQt[64][65];   // [d][q], pre-scaled by 1/8
    __shared__ float sKt[64][65];   // [d][k]
    __shared__ float sV[64][64];    // [k][d]
    __shared__ float sP[64][68];    // [q][k]
    int hh = blockIdx.y;
    int q0 = blockIdx.x * 64;
    int t = threadIdx.x;
    int tx = t & 15, ty = t >> 4;
    const float* Qh = Q + hh * 64;
    const float* Kh = K + hh * 64;
    const float* Vh = V + hh * 64;

    // stage Q transposed
#pragma unroll
    for (int j = 0; j < 4; ++j) {
        int idx = t + j * 256;
        int row = idx >> 4, col = (idx & 15) << 2;
        int gr = q0 + row;
        float4 q4 = make_float4(0.f, 0.f, 0.f, 0.f);
        if (gr < Sq) q4 = *(const float4*)(Qh + (size_t)gr * qs + col);
        sQt[col + 0][row] = q4.x * 0.125f;
        sQt[col + 1][row] = q4.y * 0.125f;
        sQt[col + 2][row] = q4.z * 0.125f;
        sQt[col + 3][row] = q4.w * 0.125f;
    }

    float m[4], l[4], o[4][4];
#pragma unroll
    for (int r = 0; r < 4; ++r) {
        m[r] = -1e30f; l[r] = 0.f;
#pragma unroll
        for (int c = 0; c < 4; ++c) o[r][c] = 0.f;
    }

    for (int k0 = 0; k0 < Sk; k0 += 64) {
        __syncthreads();   // prev PV done before overwriting sKt/sV
        // stage K^T, V
#pragma unroll
        for (int j = 0; j < 4; ++j) {
            int idx = t + j * 256;
            int row = idx >> 4, col = (idx & 15) << 2;
            int gr = k0 + row;
            float4 k4 = make_float4(0.f, 0.f, 0.f, 0.f), v4 = k4;
            if (gr < Sk) {
                k4 = *(const float4*)(Kh + (size_t)gr * ks + col);
                v4 = *(const float4*)(Vh + (size_t)gr * vs + col);
            }
            sKt[col + 0][row] = k4.x;
            sKt[col + 1][row] = k4.y;
            sKt[col + 2][row] = k4.z;
            sKt[col + 3][row] = k4.w;
            *(float4*)&sV[row][col] = v4;
        }
        __syncthreads();
        // scores: s[r][c] = q(ty*4+r) . k(tx*4+c) / 8
        float s[4][4];
#pragma unroll
        for (int r = 0; r < 4; ++r)
#pragma unroll
            for (int c = 0; c < 4; ++c) s[r][c] = 0.f;
#pragma unroll
        for (int d = 0; d < 64; ++d) {
            float4 a4 = *(const float4*)&sQt[d][ty << 2];
            float4 b4 = *(const float4*)&sKt[d][tx << 2];
            float av[4] = {a4.x, a4.y, a4.z, a4.w};
            float bv[4] = {b4.x, b4.y, b4.z, b4.w};
#pragma unroll
            for (int r = 0; r < 4; ++r)
#pragma unroll
                for (int c = 0; c < 4; ++c) s[r][c] = fmaf(av[r], bv[c], s[r][c]);
        }
        if (k0 + 64 > Sk) {
#pragma unroll
            for (int c = 0; c < 4; ++c)
                if (k0 + (tx << 2) + c >= Sk)
#pragma unroll
                    for (int r = 0; r < 4; ++r) s[r][c] = -1e30f;
        }
        // online softmax per row (parallel, shuffle over 16 tx-lanes)
#pragma unroll
        for (int r = 0; r < 4; ++r) {
            float mr = fmaxf(fmaxf(s[r][0], s[r][1]), fmaxf(s[r][2], s[r][3]));
#pragma unroll
            for (int off = 1; off < 16; off <<= 1) mr = fmaxf(mr, __shfl_xor(mr, off));
            float mn = fmaxf(m[r], mr);
            float alpha = __expf(m[r] - mn);
            m[r] = mn;
            float pv0 = __expf(s[r][0] - mn);
            float pv1 = __expf(s[r][1] - mn);
            float pv2 = __expf(s[r][2] - mn);
            float pv3 = __expf(s[r][3] - mn);
            float ls = pv0 + pv1 + pv2 + pv3;
#pragma unroll
            for (int off = 1; off < 16; off <<= 1) ls += __shfl_xor(ls, off);
            l[r] = l[r] * alpha + ls;
            float4 p4 = make_float4(pv0, pv1, pv2, pv3);
            *(float4*)&sP[(ty << 2) + r][tx << 2] = p4;
#pragma unroll
            for (int c = 0; c < 4; ++c) o[r][c] *= alpha;
        }
        __syncthreads();
        // PV: o[r][c] += sum_k P[q][k] * V[k][d]
#pragma unroll
        for (int kk = 0; kk < 16; ++kk) {
            float4 pr[4], vr[4];
#pragma unroll
            for (int r = 0; r < 4; ++r) pr[r] = *(const float4*)&sP[(ty << 2) + r][kk << 2];
#pragma unroll
            for (int j = 0; j < 4; ++j) vr[j] = *(const float4*)&sV[(kk << 2) + j][tx << 2];
#pragma unroll
            for (int r = 0; r < 4; ++r) {
                float pj[4] = {pr[r].x, pr[r].y, pr[r].z, pr[r].w};
#pragma unroll
                for (int j = 0; j < 4; ++j) {
                    o[r][0] = fmaf(pj[j], vr[j].x, o[r][0]);
                    o[r][1] = fmaf(pj[j], vr[j].y, o[r][1]);
                    o[r][2] = fmaf(pj[j], vr[j].z, o[r][2]);
                    o[r][3] = fmaf(pj[j], vr[j].w, o[r][3]);
                }
            }
        }
    }
#pragma unroll
    for (int r = 0; r < 4; ++r) {
        int q = q0 + (ty << 2) + r;
        if (q < Sq) {
            float inv = 1.f / l[r];
            float4 o4 = make_float4(o[r][0] * inv, o[r][1] * inv, o[r][2] * inv, o[r][3] * inv);
            *(float4*)(O + (size_t)q * os + hh * 64 + (tx << 2)) = o4;
        }
    }
}

// h += (g ? g[c]* : 1*) p   (float4 over S*1024)
__global__ void resid_kernel(float* __restrict__ h, const float* __restrict__ p,
                             const float* __restrict__ g, int n4) {
    int i = blockIdx.x * 256 + threadIdx.x;
    if (i >= n4) return;
    float4 hv = ((float4*)h)[i];
    float4 pv = ((const float4*)p)[i];
    if (g) {
        int c = (i & 255) << 2;
        hv.x += g[c] * pv.x;
        hv.y += g[c + 1] * pv.y;
        hv.z += g[c + 2] * pv.z;
        hv.w += g[c + 3] * pv.w;
    } else {
        hv.x += pv.x; hv.y += pv.y; hv.z += pv.z; hv.w += pv.w;
    }
    ((float4*)h)[i] = hv;
}

// out[c][l] = hn[5+l] . out_w[:,c] + out_b[c]
__global__ void out_kernel(const float* __restrict__ hn, const float* __restrict__ out_w,
                           const float* __restrict__ out_b, float* __restrict__ out) {
    int id = blockIdx.x * 256 + threadIdx.x;
    if (id >= 4096 * 8) return;
    int l = id >> 3, c = id & 7;
    const float* row = hn + (size_t)(5 + l) * CDIM;
    float acc = out_b[c];
    for (int k = 0; k < 1024; ++k) acc = fmaf(row[k], out_w[k * 8 + c], acc);
    out[c * 4096 + l] = acc;
}

extern "C" void kernel_launch(void* const* d_in, const int* in_sizes, int n_in,
                              void* d_out, int out_size, void* d_ws, size_t ws_size,
                              hipStream_t stream) {
    const float* x        = (const float*)d_in[0];
    const float* t        = (const float*)d_in[1];
    const float* cond     = (const float*)d_in[2];
    const float* t_w1     = (const float*)d_in[3];
    const float* t_b1     = (const float*)d_in[4];
    const float* t_w2     = (const float*)d_in[5];
    const float* t_b2     = (const float*)d_in[6];
    const float* in_w     = (const float*)d_in[7];
    const float* in_b     = (const float*)d_in[8];
    const float* pos_tok  = (const float*)d_in[9];
    const float* reg_tok  = (const float*)d_in[10];
    const float* ada_w    = (const float*)d_in[11];
    const float* ada_b    = (const float*)d_in[12];
    const float* qkv_w    = (const float*)d_in[13];
    const float* qkv_b    = (const float*)d_in[14];
    const float* q_gamma  = (const float*)d_in[15];
    const float* k_gamma  = (const float*)d_in[16];
    const float* attn_ow  = (const float*)d_in[17];
    const float* attn_ob  = (const float*)d_in[18];
    const float* n2_w     = (const float*)d_in[19];
    const float* n2_b     = (const float*)d_in[20];
    const float* cq_w     = (const float*)d_in[21];
    const float* cq_b     = (const float*)d_in[22];
    const float* ckv_w    = (const float*)d_in[23];
    const float* ckv_b    = (const float*)d_in[24];
    const float* co_w     = (const float*)d_in[25];
    const float* co_b     = (const float*)d_in[26];
    const float* mlp_w1   = (const float*)d_in[27];
    const float* mlp_b1   = (const float*)d_in[28];
    const float* mlp_w2   = (const float*)d_in[29];
    const float* mlp_b2   = (const float*)d_in[30];
    const float* out_w    = (const float*)d_in[31];
    const float* out_b    = (const float*)d_in[32];

    const int S = S_TOK;
    float* ws = (float*)d_ws;
    float* h    = ws;
    float* hn   = h + (size_t)S * 1024;
    float* D    = hn + (size_t)S * 1024;        // S*4096: qkv / q+kv / ff1
    float* E    = D + (size_t)S * 4096;         // S*1024: sdpa out
    float* F    = E + (size_t)S * 1024;         // S*1024: proj out
    float* tf   = F + (size_t)S * 1024;
    float* s1   = tf + 256;
    float* temb = s1 + 1024;
    float* stemb = temb + 1024;
    float* mod  = stemb + 1024;                 // 4*6144

    // temb / adaLN modulation chain
    tfreq_kernel<<<1, 256, 0, stream>>>(t, tf);
    gemv_kernel<<<4, 256, 0, stream>>>(tf, t_w1, 1024, t_b1, s1, 256, 1024, 1);
    gemv_kernel<<<4, 256, 0, stream>>>(s1, t_w2, 1024, t_b2, temb, 1024, 1024, 0);
    silu_kernel<<<4, 256, 0, stream>>>(temb, stemb, 1024);
    mod_kernel<<<96, 256, 0, stream>>>(stemb, ada_w, ada_b, mod);

    // input embed + pos emb + tokens
    embed_kernel<<<(S * 1024 + 255) / 256, 256, 0, stream>>>(x, in_w, in_b, pos_tok, reg_tok, h);

    int gy = (S + 63) / 64;     // 65
    int aqx = (S + 63) / 64;    // 65 query-blocks of 64
    for (int i = 0; i < 4; ++i) {
        const float* modb = mod + i * 6144;
        // hn = ln(h)*(1+sc1)+sh1
        ln_kernel<<<S, 256, 0, stream>>>(h, hn, modb + 1024, modb + 0, 1);
        // qkv = hn @ qkv_w + qkv_b
        sgemm_kernel<<<dim3(3072 / 64, gy), 256, 0, stream>>>(hn, 1024, qkv_w + (size_t)i * 1024 * 3072, 3072,
                                                              D, 3072, S, 3072, 1024, qkv_b + i * 3072, 0);
        // rms+gamma on q,k
        rms_kernel<<<(2 * S * 16 * 64 + 255) / 256, 256, 0, stream>>>(D, q_gamma + i * 1024, k_gamma + i * 1024, S);
        // self attention
        attn_kernel<<<dim3(aqx, 16), 256, 0, stream>>>(D, 3072, D + 1024, 3072, D + 2048, 3072, E, 1024, S, S);
        // o-proj
        sgemm_kernel<<<dim3(16, gy), 256, 0, stream>>>(E, 1024, attn_ow + (size_t)i * 1024 * 1024, 1024,
                                                       F, 1024, S, 1024, 1024, attn_ob + i * 1024, 0);
        // h += g1 * o
        resid_kernel<<<S, 256, 0, stream>>>(h, F, modb + 2 * 1024, S * 256);

        // hn = ln(h, n2_w, n2_b)
        ln_kernel<<<S, 256, 0, stream>>>(h, hn, n2_w + i * 1024, n2_b + i * 1024, 2);
        // q = hn @ cq_w
        sgemm_kernel<<<dim3(16, gy), 256, 0, stream>>>(hn, 1024, cq_w + (size_t)i * 1024 * 1024, 1024,
                                                       D, 1024, S, 1024, 1024, cq_b + i * 1024, 0);
        // kv = cond @ ckv_w
        float* kvD = D + (size_t)S * 1024;
        sgemm_kernel<<<dim3(32, 16), 256, 0, stream>>>(cond, 1024, ckv_w + (size_t)i * 1024 * 2048, 2048,
                                                       kvD, 2048, 1024, 2048, 1024, ckv_b + i * 2048, 0);
        // cross attention
        attn_kernel<<<dim3(aqx, 16), 256, 0, stream>>>(D, 1024, kvD, 2048, kvD + 1024, 2048, E, 1024, S, 1024);
        // co proj
        sgemm_kernel<<<dim3(16, gy), 256, 0, stream>>>(E, 1024, co_w + (size_t)i * 1024 * 1024, 1024,
                                                       F, 1024, S, 1024, 1024, co_b + i * 1024, 0);
        // h += o
        resid_kernel<<<S, 256, 0, stream>>>(h, F, nullptr, S * 256);

        // hn = ln(h)*(1+sc2)+sh2
        ln_kernel<<<S, 256, 0, stream>>>(h, hn, modb + 4 * 1024, modb + 3 * 1024, 1);
        // ff1 = gelu(hn @ mlp_w1 + b1)
        sgemm_kernel<<<dim3(64, gy), 256, 0, stream>>>(hn, 1024, mlp_w1 + (size_t)i * 1024 * 4096, 4096,
                                                       D, 4096, S, 4096, 1024, mlp_b1 + i * 4096, 1);
        // ff2 = ff1 @ mlp_w2 + b2
        sgemm_kernel<<<dim3(16, gy), 256, 0, stream>>>(D, 4096, mlp_w2 + (size_t)i * 4096 * 1024, 1024,
                                                       F, 1024, S, 1024, 4096, mlp_b2 + i * 1024, 0);
        // h += g2 * ff
        resid_kernel<<<S, 256, 0, stream>>>(h, F, modb + 5 * 1024, S * 256);
    }
    // final LN + out proj + transpose
    ln_kernel<<<S, 256, 0, stream>>>(h, hn, nullptr, nullptr, 0);
    out_kernel<<<128, 256, 0, stream>>>(hn, out_w, out_b, (float*)d_out);
}

// Round 3
// 8995.572 us; speedup vs baseline: 5.6412x; 2.2362x over previous
//
#include <hip/hip_runtime.h>
#include <math.h>

#define S_TOK 4101
#define CDIM 1024

typedef unsigned short u16;
typedef u16 us8 __attribute__((ext_vector_type(8)));
typedef u16 us4 __attribute__((ext_vector_type(4)));
typedef __bf16 bf16x8 __attribute__((ext_vector_type(8)));
typedef float f32x4 __attribute__((ext_vector_type(4)));

__device__ __forceinline__ float silu_f(float x) { return x / (1.f + expf(-x)); }
__device__ __forceinline__ float gelu_f(float x) { return 0.5f * x * (1.f + erff(x * 0.70710678118654752f)); }
__device__ __forceinline__ u16 f2b(float x) {
    unsigned u = __float_as_uint(x);
    unsigned r = (u + 0x7FFFu + ((u >> 16) & 1u)) >> 16;
    return (u16)r;
}
__device__ __forceinline__ float b2f(u16 u) { return __uint_as_float(((unsigned)u) << 16); }

// ---------------- t-freq embedding ----------------
__global__ void tfreq_kernel(const float* __restrict__ t, float* __restrict__ tf) {
    int i = threadIdx.x;
    float tv = t[0];
    int f = i & 127;
    float fr = expf(-logf(10000.f) * (float)f / 128.f);
    float a = tv * fr;
    tf[i] = (i < 128) ? cosf(a) : sinf(a);
}

__global__ void gemv_kernel(const float* __restrict__ in, const float* __restrict__ W, int ldw,
                            const float* __restrict__ bias, float* __restrict__ out,
                            int K, int N, int act) {
    int j = blockIdx.x * blockDim.x + threadIdx.x;
    if (j >= N) return;
    float acc = bias ? bias[j] : 0.f;
    for (int i = 0; i < K; ++i) acc = fmaf(in[i], W[(size_t)i * ldw + j], acc);
    if (act == 1) acc = silu_f(acc);
    out[j] = acc;
}

__global__ void silu_kernel(const float* __restrict__ in, float* __restrict__ out, int n) {
    int i = blockIdx.x * blockDim.x + threadIdx.x;
    if (i < n) out[i] = silu_f(in[i]);
}

__global__ void mod_kernel(const float* __restrict__ stemb, const float* __restrict__ ada_w,
                           const float* __restrict__ ada_b, float* __restrict__ mod) {
    int j = blockIdx.x * blockDim.x + threadIdx.x;
    if (j >= 4 * 6144) return;
    int b = j / 6144, c = j % 6144;
    const float* W = ada_w + (size_t)b * 1024 * 6144 + c;
    float acc = ada_b[j];
    for (int i = 0; i < 1024; ++i) acc = fmaf(stemb[i], W[(size_t)i * 6144], acc);
    mod[j] = acc;
}

__global__ void embed_kernel(const float* __restrict__ x, const float* __restrict__ in_w,
                             const float* __restrict__ in_b, const float* __restrict__ pos_token,
                             const float* __restrict__ reg_token, float* __restrict__ h) {
    int id = blockIdx.x * 256 + threadIdx.x;
    if (id >= S_TOK * CDIM) return;
    int row = id >> 10, c = id & 1023;
    float v;
    if (row == 0) v = pos_token[c];
    else if (row < 5) v = reg_token[(row - 1) * 1024 + c];
    else {
        int l = row - 5;
        float acc = in_b[c];
#pragma unroll
        for (int ch = 0; ch < 8; ++ch) acc = fmaf(x[ch * 4096 + l], in_w[ch * 1024 + c], acc);
        float pe = 0.f;
        if (c < 1020) {
            int coordIdx = c / 340, r2 = c % 340;
            int coord;
            if (coordIdx == 0) coord = l >> 8;
            else if (coordIdx == 1) coord = (l >> 4) & 15;
            else coord = l & 15;
            int f = (r2 < 170) ? r2 : r2 - 170;
            float fr = expf(-logf(10000.f) * (float)f / 170.f);
            float a = (float)coord * fr;
            pe = (r2 < 170) ? sinf(a) : cosf(a);
        }
        v = acc + pe;
    }
    h[id] = v;
}

// ---------------- LayerNorm (fp32 in, bf16 out): mode 0 plain, 1: *(1+w)+b, 2: *w+b
__global__ __launch_bounds__(256) void ln_kernel(const float* __restrict__ X, u16* __restrict__ Y,
                                                 const float* __restrict__ w, const float* __restrict__ b,
                                                 int mode) {
    int row = blockIdx.x;
    const float* x = X + (size_t)row * CDIM;
    float4 v = ((const float4*)x)[threadIdx.x];
    float s = v.x + v.y + v.z + v.w;
    float ss = v.x * v.x + v.y * v.y + v.z * v.z + v.w * v.w;
#pragma unroll
    for (int o = 32; o > 0; o >>= 1) { s += __shfl_xor(s, o); ss += __shfl_xor(ss, o); }
    __shared__ float sa[4], sb[4];
    int wv = threadIdx.x >> 6;
    if ((threadIdx.x & 63) == 0) { sa[wv] = s; sb[wv] = ss; }
    __syncthreads();
    s = sa[0] + sa[1] + sa[2] + sa[3];
    ss = sb[0] + sb[1] + sb[2] + sb[3];
    float mean = s * (1.f / 1024.f);
    float var = ss * (1.f / 1024.f) - mean * mean;
    float r = rsqrtf(var + 1e-6f);
    int c = threadIdx.x << 2;
    float t0 = (v.x - mean) * r, t1 = (v.y - mean) * r, t2 = (v.z - mean) * r, t3 = (v.w - mean) * r;
    float o0, o1, o2, o3;
    if (mode == 0) { o0 = t0; o1 = t1; o2 = t2; o3 = t3; }
    else if (mode == 1) {
        o0 = t0 * (1.f + w[c]) + b[c];
        o1 = t1 * (1.f + w[c + 1]) + b[c + 1];
        o2 = t2 * (1.f + w[c + 2]) + b[c + 2];
        o3 = t3 * (1.f + w[c + 3]) + b[c + 3];
    } else {
        o0 = t0 * w[c] + b[c];
        o1 = t1 * w[c + 1] + b[c + 1];
        o2 = t2 * w[c + 2] + b[c + 2];
        o3 = t3 * w[c + 3] + b[c + 3];
    }
    union { u16 u[4]; us4 v4; } pk;
    pk.u[0] = f2b(o0); pk.u[1] = f2b(o1); pk.u[2] = f2b(o2); pk.u[3] = f2b(o3);
    ((us4*)(Y + (size_t)row * CDIM))[threadIdx.x] = pk.v4;
}

// ---------------- weight transpose + fp32->bf16: W[K][N] -> Wt[N][K] ----------------
__global__ __launch_bounds__(256) void wtrans_kernel(const float* __restrict__ W, u16* __restrict__ Wt,
                                                     int K, int N) {
    __shared__ u16 s[64 * 72];
    int n0 = blockIdx.x * 64, k0 = blockIdx.y * 64;
    int t = threadIdx.x;
    int kk = t >> 4, n4 = (t & 15) * 4;
#pragma unroll
    for (int i = 0; i < 4; ++i) {
        int k = kk + i * 16;
        float4 w4 = *(const float4*)(W + (size_t)(k0 + k) * N + n0 + n4);
        s[(n4 + 0) * 72 + k] = f2b(w4.x);
        s[(n4 + 1) * 72 + k] = f2b(w4.y);
        s[(n4 + 2) * 72 + k] = f2b(w4.z);
        s[(n4 + 3) * 72 + k] = f2b(w4.w);
    }
    __syncthreads();
    int n = t >> 2, kh = (t & 3) * 16;
    u16* dst = Wt + (size_t)(n0 + n) * K + k0 + kh;
    *(us8*)dst = *(const us8*)&s[n * 72 + kh];
    *(us8*)(dst + 8) = *(const us8*)&s[n * 72 + kh + 8];
}

// fp32 -> bf16 elementwise
__global__ void cvt_kernel(const float* __restrict__ src, u16* __restrict__ dst, int n) {
    int i = blockIdx.x * 256 + threadIdx.x;
    if (i < n) dst[i] = f2b(src[i]);
}

// ---------------- bf16 MFMA GEMM: C[M,N] = A[M,K] @ B[K,N](as Bt[N][K]) + bias ----------------
// 128x128 tile, BK=32, 256 threads = 4 waves (2x2), each wave 64x64 = 4x4 MFMA tiles.
__global__ __launch_bounds__(256) void bgemm_kernel(const u16* __restrict__ A, int lda,
                                                    const u16* __restrict__ Bt, int ldbt,
                                                    float* __restrict__ C, u16* __restrict__ Cb, int ldc,
                                                    int M, int N, int K,
                                                    const float* __restrict__ bias, int act) {
    __shared__ u16 As[128 * 40];
    __shared__ u16 Bs[128 * 40];
    int t = threadIdx.x;
    int w = t >> 6, lane = t & 63, quad = lane >> 4, l15 = lane & 15;
    int wm = w & 1, wn = w >> 1;
    int m0 = blockIdx.y * 128, n0 = blockIdx.x * 128;
    int sr = t >> 1, skh = (t & 1) * 16;
    int arow = m0 + sr; if (arow >= M) arow = M - 1;
    const u16* ap = A + (size_t)arow * lda + skh;
    const u16* bp = Bt + (size_t)(n0 + sr) * ldbt + skh;
    u16* asw = &As[sr * 40 + skh];
    u16* bsw = &Bs[sr * 40 + skh];
    f32x4 acc[4][4];
#pragma unroll
    for (int i = 0; i < 4; ++i)
#pragma unroll
        for (int j = 0; j < 4; ++j) acc[i][j] = (f32x4){0.f, 0.f, 0.f, 0.f};
    const u16* ar = &As[(wm * 64 + l15) * 40 + quad * 8];
    const u16* br = &Bs[(wn * 64 + l15) * 40 + quad * 8];
    for (int k0 = 0; k0 < K; k0 += 32) {
        us8 a0 = *(const us8*)(ap + k0);
        us8 a1 = *(const us8*)(ap + k0 + 8);
        us8 b0 = *(const us8*)(bp + k0);
        us8 b1 = *(const us8*)(bp + k0 + 8);
        *(us8*)asw = a0; *(us8*)(asw + 8) = a1;
        *(us8*)bsw = b0; *(us8*)(bsw + 8) = b1;
        __syncthreads();
        bf16x8 af[4], bfr[4];
#pragma unroll
        for (int mt = 0; mt < 4; ++mt) af[mt] = *(const bf16x8*)(ar + mt * 16 * 40);
#pragma unroll
        for (int nt = 0; nt < 4; ++nt) bfr[nt] = *(const bf16x8*)(br + nt * 16 * 40);
#pragma unroll
        for (int mt = 0; mt < 4; ++mt)
#pragma unroll
            for (int nt = 0; nt < 4; ++nt)
                acc[mt][nt] = __builtin_amdgcn_mfma_f32_16x16x32_bf16(af[mt], bfr[nt], acc[mt][nt], 0, 0, 0);
        __syncthreads();
    }
#pragma unroll
    for (int nt = 0; nt < 4; ++nt) {
        int ncol = n0 + wn * 64 + nt * 16 + l15;
        float bv = bias[ncol];
#pragma unroll
        for (int mt = 0; mt < 4; ++mt) {
#pragma unroll
            for (int r = 0; r < 4; ++r) {
                int row = m0 + wm * 64 + mt * 16 + quad * 4 + r;
                if (row < M) {
                    float v = acc[mt][nt][r] + bv;
                    if (act) v = gelu_f(v);
                    if (Cb) Cb[(size_t)row * ldc + ncol] = f2b(v);
                    else C[(size_t)row * ldc + ncol] = v;
                }
            }
        }
    }
}

// ---------------- RMS-norm * gamma on q,k slices of qkv buffer (fp32) ----------------
__global__ void rms_kernel(float* __restrict__ qkv, const float* __restrict__ qg,
                           const float* __restrict__ kg, int S) {
    int gid = blockIdx.x * blockDim.x + threadIdx.x;
    int wid = gid >> 6;
    int lane = gid & 63;
    int total = 2 * S * 16;
    if (wid >= total) return;
    int isK = (wid >= S * 16) ? 1 : 0;
    int rem = isK ? (wid - S * 16) : wid;
    int s = rem / 16, hh = rem % 16;
    float* p = qkv + (size_t)s * 3072 + isK * 1024 + hh * 64 + lane;
    float v = *p;
    float sq = v * v;
#pragma unroll
    for (int o = 32; o > 0; o >>= 1) sq += __shfl_xor(sq, o);
    float r = rsqrtf(sq * (1.f / 64.f) + 1e-6f);
    const float* g = isK ? kg : qg;
    *p = v * r * g[hh * 64 + lane];
}

// ---------------- MFMA flash attention (fp32 in, bf16 out) ----------------
// 256 threads = 4 waves; wave w owns 16 queries. Computes S^T = K.Q^T so both
// MFMA operands read k-contiguous; softmax in D-layout regs; P via LDS; PV = P.V
// with V transposed at staging. HD=64, NH=16.
__global__ __launch_bounds__(256) void attn_kernel(const float* __restrict__ Q, int qs,
                                                   const float* __restrict__ K, int ks,
                                                   const float* __restrict__ V, int vs,
                                                   u16* __restrict__ O, int os,
                                                   int Sq, int Sk) {
    __shared__ u16 sK[64 * 72];
    __shared__ u16 sVt[64 * 72];
    __shared__ u16 sP[64 * 72];
    int hh = blockIdx.y;
    int q0 = blockIdx.x * 64;
    int t = threadIdx.x;
    int w = t >> 6, lane = t & 63, quad = lane >> 4, l15 = lane & 15;
    // Q fragments, scaled by 1/8 (B-operand of S^T = K.Q^T)
    int qrow = q0 + w * 16 + l15; if (qrow >= Sq) qrow = Sq - 1;
    const float* qp = Q + (size_t)qrow * qs + hh * 64 + quad * 8;
    bf16x8 bq[2];
#pragma unroll
    for (int c = 0; c < 2; ++c) {
        float4 x = *(const float4*)(qp + c * 32);
        float4 y = *(const float4*)(qp + c * 32 + 4);
        union { u16 u[8]; bf16x8 v; } pk;
        pk.u[0] = f2b(x.x * 0.125f); pk.u[1] = f2b(x.y * 0.125f);
        pk.u[2] = f2b(x.z * 0.125f); pk.u[3] = f2b(x.w * 0.125f);
        pk.u[4] = f2b(y.x * 0.125f); pk.u[5] = f2b(y.y * 0.125f);
        pk.u[6] = f2b(y.z * 0.125f); pk.u[7] = f2b(y.w * 0.125f);
        bq[c] = pk.v;
    }
    float m_run = -3e38f, l_run = 0.f;
    f32x4 oacc[4];
#pragma unroll
    for (int nt = 0; nt < 4; ++nt) oacc[nt] = (f32x4){0.f, 0.f, 0.f, 0.f};
    int skey = t >> 2;
    int sd = (t & 3) * 16;
    const float4 z4 = make_float4(0.f, 0.f, 0.f, 0.f);
    for (int k0 = 0; k0 < Sk; k0 += 64) {
        __syncthreads();
        bool kval = (k0 + skey) < Sk;
        // stage K natural [key][d]
        const float* kp = K + (size_t)(k0 + skey) * ks + hh * 64 + sd;
#pragma unroll
        for (int p = 0; p < 2; ++p) {
            float4 a = kval ? *(const float4*)(kp + p * 8) : z4;
            float4 b = kval ? *(const float4*)(kp + p * 8 + 4) : z4;
            union { u16 u[8]; us8 v; } pk;
            pk.u[0] = f2b(a.x); pk.u[1] = f2b(a.y); pk.u[2] = f2b(a.z); pk.u[3] = f2b(a.w);
            pk.u[4] = f2b(b.x); pk.u[5] = f2b(b.y); pk.u[6] = f2b(b.z); pk.u[7] = f2b(b.w);
            *(us8*)&sK[skey * 72 + sd + p * 8] = pk.v;
        }
        // stage V transposed [d][key], pair-packed b32 writes
        {
            const float* vp = V + (size_t)(k0 + skey) * vs + hh * 64 + sd;
            float vv[16];
#pragma unroll
            for (int i = 0; i < 4; ++i) {
                float4 v4 = kval ? *(const float4*)(vp + 4 * i) : z4;
                vv[4 * i + 0] = v4.x; vv[4 * i + 1] = v4.y;
                vv[4 * i + 2] = v4.z; vv[4 * i + 3] = v4.w;
            }
            float ov[16];
#pragma unroll
            for (int i = 0; i < 16; ++i) ov[i] = __shfl_xor(vv[i], 4);
            int keyE = skey & ~1;
            if ((skey & 1) == 0) {
#pragma unroll
                for (int i = 0; i < 8; ++i) {
                    unsigned u = (unsigned)f2b(vv[i]) | ((unsigned)f2b(ov[i]) << 16);
                    *(unsigned*)&sVt[(sd + i) * 72 + keyE] = u;
                }
            } else {
#pragma unroll
                for (int i = 8; i < 16; ++i) {
                    unsigned u = (unsigned)f2b(ov[i]) | ((unsigned)f2b(vv[i]) << 16);
                    *(unsigned*)&sVt[(sd + i) * 72 + keyE] = u;
                }
            }
        }
        __syncthreads();
        // scores S^T[key][q]
        f32x4 sc[4];
#pragma unroll
        for (int mt = 0; mt < 4; ++mt) {
            bf16x8 a0 = *(const bf16x8*)&sK[(mt * 16 + l15) * 72 + quad * 8];
            bf16x8 a1 = *(const bf16x8*)&sK[(mt * 16 + l15) * 72 + 32 + quad * 8];
            f32x4 z = (f32x4){0.f, 0.f, 0.f, 0.f};
            z = __builtin_amdgcn_mfma_f32_16x16x32_bf16(a0, bq[0], z, 0, 0, 0);
            z = __builtin_amdgcn_mfma_f32_16x16x32_bf16(a1, bq[1], z, 0, 0, 0);
            sc[mt] = z;
        }
        // mask invalid keys
#pragma unroll
        for (int mt = 0; mt < 4; ++mt)
#pragma unroll
            for (int r = 0; r < 4; ++r)
                if (k0 + mt * 16 + quad * 4 + r >= Sk) sc[mt][r] = -3e38f;
        // online softmax per q (= l15 column), reduce across quads
        float mx = -3e38f;
#pragma unroll
        for (int mt = 0; mt < 4; ++mt)
#pragma unroll
            for (int r = 0; r < 4; ++r) mx = fmaxf(mx, sc[mt][r]);
        mx = fmaxf(mx, __shfl_xor(mx, 16));
        mx = fmaxf(mx, __shfl_xor(mx, 32));
        float mn = fmaxf(m_run, mx);
        float alpha = __expf(m_run - mn);
        float ls = 0.f;
#pragma unroll
        for (int mt = 0; mt < 4; ++mt)
#pragma unroll
            for (int r = 0; r < 4; ++r) {
                float p = __expf(sc[mt][r] - mn);
                sc[mt][r] = p;
                ls += p;
            }
        ls += __shfl_xor(ls, 16);
        ls += __shfl_xor(ls, 32);
        l_run = l_run * alpha + ls;
        m_run = mn;
        // write P rows (q-major) as bf16
#pragma unroll
        for (int mt = 0; mt < 4; ++mt) {
            union { u16 u[4]; us4 v; } pk;
            pk.u[0] = f2b(sc[mt][0]); pk.u[1] = f2b(sc[mt][1]);
            pk.u[2] = f2b(sc[mt][2]); pk.u[3] = f2b(sc[mt][3]);
            *(us4*)&sP[(w * 16 + l15) * 72 + mt * 16 + quad * 4] = pk.v;
        }
        // rescale O by alpha of each output row q' = quad*4+r
        float alr[4];
#pragma unroll
        for (int r = 0; r < 4; ++r) alr[r] = __shfl(alpha, (lane & 48) | (quad * 4 + r));
#pragma unroll
        for (int nt = 0; nt < 4; ++nt)
#pragma unroll
            for (int r = 0; r < 4; ++r) oacc[nt][r] *= alr[r];
        // PV
#pragma unroll
        for (int c = 0; c < 2; ++c) {
            bf16x8 pa = *(const bf16x8*)&sP[(w * 16 + l15) * 72 + c * 32 + quad * 8];
#pragma unroll
            for (int nt = 0; nt < 4; ++nt) {
                bf16x8 vb = *(const bf16x8*)&sVt[(nt * 16 + l15) * 72 + c * 32 + quad * 8];
                oacc[nt] = __builtin_amdgcn_mfma_f32_16x16x32_bf16(pa, vb, oacc[nt], 0, 0, 0);
            }
        }
    }
    float lr[4];
#pragma unroll
    for (int r = 0; r < 4; ++r) lr[r] = __shfl(l_run, (lane & 48) | (quad * 4 + r));
#pragma unroll
    for (int r = 0; r < 4; ++r) {
        int q = q0 + w * 16 + quad * 4 + r;
        if (q < Sq) {
            float inv = 1.f / lr[r];
#pragma unroll
            for (int nt = 0; nt < 4; ++nt)
                O[(size_t)q * os + hh * 64 + nt * 16 + l15] = f2b(oacc[nt][r] * inv);
        }
    }
}

// h += (g ? g[c]* : 1*) p
__global__ void resid_kernel(float* __restrict__ h, const float* __restrict__ p,
                             const float* __restrict__ g, int n4) {
    int i = blockIdx.x * 256 + threadIdx.x;
    if (i >= n4) return;
    float4 hv = ((float4*)h)[i];
    float4 pv = ((const float4*)p)[i];
    if (g) {
        int c = (i & 255) << 2;
        hv.x += g[c] * pv.x;
        hv.y += g[c + 1] * pv.y;
        hv.z += g[c + 2] * pv.z;
        hv.w += g[c + 3] * pv.w;
    } else {
        hv.x += pv.x; hv.y += pv.y; hv.z += pv.z; hv.w += pv.w;
    }
    ((float4*)h)[i] = hv;
}

// out[c][l] = hn_bf16[5+l] . out_w[:,c] + out_b[c]
__global__ void out_kernel(const u16* __restrict__ hn, const float* __restrict__ out_w,
                           const float* __restrict__ out_b, float* __restrict__ out) {
    int id = blockIdx.x * 256 + threadIdx.x;
    if (id >= 4096 * 8) return;
    int l = id >> 3, c = id & 7;
    const u16* row = hn + (size_t)(5 + l) * CDIM;
    float acc = out_b[c];
    for (int k = 0; k < 1024; ++k) acc = fmaf(b2f(row[k]), out_w[k * 8 + c], acc);
    out[c * 4096 + l] = acc;
}

extern "C" void kernel_launch(void* const* d_in, const int* in_sizes, int n_in,
                              void* d_out, int out_size, void* d_ws, size_t ws_size,
                              hipStream_t stream) {
    const float* x        = (const float*)d_in[0];
    const float* t        = (const float*)d_in[1];
    const float* cond     = (const float*)d_in[2];
    const float* t_w1     = (const float*)d_in[3];
    const float* t_b1     = (const float*)d_in[4];
    const float* t_w2     = (const float*)d_in[5];
    const float* t_b2     = (const float*)d_in[6];
    const float* in_w     = (const float*)d_in[7];
    const float* in_b     = (const float*)d_in[8];
    const float* pos_tok  = (const float*)d_in[9];
    const float* reg_tok  = (const float*)d_in[10];
    const float* ada_w    = (const float*)d_in[11];
    const float* ada_b    = (const float*)d_in[12];
    const float* qkv_w    = (const float*)d_in[13];
    const float* qkv_b    = (const float*)d_in[14];
    const float* q_gamma  = (const float*)d_in[15];
    const float* k_gamma  = (const float*)d_in[16];
    const float* attn_ow  = (const float*)d_in[17];
    const float* attn_ob  = (const float*)d_in[18];
    const float* n2_w     = (const float*)d_in[19];
    const float* n2_b     = (const float*)d_in[20];
    const float* cq_w     = (const float*)d_in[21];
    const float* cq_b     = (const float*)d_in[22];
    const float* ckv_w    = (const float*)d_in[23];
    const float* ckv_b    = (const float*)d_in[24];
    const float* co_w     = (const float*)d_in[25];
    const float* co_b     = (const float*)d_in[26];
    const float* mlp_w1   = (const float*)d_in[27];
    const float* mlp_b1   = (const float*)d_in[28];
    const float* mlp_w2   = (const float*)d_in[29];
    const float* mlp_b2   = (const float*)d_in[30];
    const float* out_w    = (const float*)d_in[31];
    const float* out_b    = (const float*)d_in[32];

    const int S = S_TOK;
    const size_t SC = (size_t)S * 1024;
    float* ws = (float*)d_ws;
    float* h    = ws;                    // S*1024 fp32
    float* F    = h + SC;                // S*1024 fp32
    float* D    = F + SC;                // S*4096 fp32 (also: q | kv | ff1-bf16)
    float* tf   = D + SC * 4;
    float* s1   = tf + 256;
    float* temb = s1 + 1024;
    float* stemb = temb + 1024;
    float* mod  = stemb + 1024;          // 4*6144
    float* fend = mod + 4 * 6144;
    u16* hn    = (u16*)fend;             // S*1024 bf16
    u16* E     = hn + SC;                // S*1024 bf16
    u16* condb = E + SC;                 // 1M bf16
    u16* wt    = condb + 1024 * 1024;
    u16* wt_qkv = wt;
    u16* wt_o   = wt_qkv + (size_t)1024 * 3072;
    u16* wt_cq  = wt_o   + (size_t)1024 * 1024;
    u16* wt_ckv = wt_cq  + (size_t)1024 * 1024;
    u16* wt_co  = wt_ckv + (size_t)1024 * 2048;
    u16* wt_m1  = wt_co  + (size_t)1024 * 1024;
    u16* wt_m2  = wt_m1  + (size_t)1024 * 4096;
    float* q_buf = D;                    // cross-attn q (S*1024 fp32)
    float* kv    = D + SC;               // 1024*2048 fp32
    u16* ff1     = (u16*)D;              // S*4096 bf16

    // temb / adaLN modulation chain
    tfreq_kernel<<<1, 256, 0, stream>>>(t, tf);
    gemv_kernel<<<4, 256, 0, stream>>>(tf, t_w1, 1024, t_b1, s1, 256, 1024, 1);
    gemv_kernel<<<4, 256, 0, stream>>>(s1, t_w2, 1024, t_b2, temb, 1024, 1024, 0);
    silu_kernel<<<4, 256, 0, stream>>>(temb, stemb, 1024);
    mod_kernel<<<96, 256, 0, stream>>>(stemb, ada_w, ada_b, mod);

    // input embed + cond bf16
    embed_kernel<<<(S * 1024 + 255) / 256, 256, 0, stream>>>(x, in_w, in_b, pos_tok, reg_tok, h);
    cvt_kernel<<<4096, 256, 0, stream>>>(cond, condb, 1024 * 1024);

    int gy = (S + 127) / 128;   // 33
    int aqx = (S + 63) / 64;    // 65
    for (int i = 0; i < 4; ++i) {
        const float* modb = mod + i * 6144;
        // weight prep (transpose + bf16)
        wtrans_kernel<<<dim3(3072 / 64, 16), 256, 0, stream>>>(qkv_w + (size_t)i * 1024 * 3072, wt_qkv, 1024, 3072);
        wtrans_kernel<<<dim3(16, 16), 256, 0, stream>>>(attn_ow + (size_t)i * 1024 * 1024, wt_o, 1024, 1024);
        wtrans_kernel<<<dim3(16, 16), 256, 0, stream>>>(cq_w + (size_t)i * 1024 * 1024, wt_cq, 1024, 1024);
        wtrans_kernel<<<dim3(32, 16), 256, 0, stream>>>(ckv_w + (size_t)i * 1024 * 2048, wt_ckv, 1024, 2048);
        wtrans_kernel<<<dim3(16, 16), 256, 0, stream>>>(co_w + (size_t)i * 1024 * 1024, wt_co, 1024, 1024);
        wtrans_kernel<<<dim3(64, 16), 256, 0, stream>>>(mlp_w1 + (size_t)i * 1024 * 4096, wt_m1, 1024, 4096);
        wtrans_kernel<<<dim3(16, 64), 256, 0, stream>>>(mlp_w2 + (size_t)i * 4096 * 1024, wt_m2, 4096, 1024);

        // hn = ln(h)*(1+sc1)+sh1  (bf16)
        ln_kernel<<<S, 256, 0, stream>>>(h, hn, modb + 1024, modb + 0, 1);
        // qkv = hn @ qkv_w + b  (fp32 out)
        bgemm_kernel<<<dim3(24, gy), 256, 0, stream>>>(hn, 1024, wt_qkv, 1024, D, nullptr, 3072,
                                                       S, 3072, 1024, qkv_b + i * 3072, 0);
        rms_kernel<<<(2 * S * 16 * 64 + 255) / 256, 256, 0, stream>>>(D, q_gamma + i * 1024, k_gamma + i * 1024, S);
        // self attention -> E (bf16)
        attn_kernel<<<dim3(aqx, 16), 256, 0, stream>>>(D, 3072, D + 1024, 3072, D + 2048, 3072, E, 1024, S, S);
        // o-proj
        bgemm_kernel<<<dim3(8, gy), 256, 0, stream>>>(E, 1024, wt_o, 1024, F, nullptr, 1024,
                                                      S, 1024, 1024, attn_ob + i * 1024, 0);
        resid_kernel<<<S, 256, 0, stream>>>(h, F, modb + 2 * 1024, S * 256);

        // hn = ln(h, n2_w, n2_b)
        ln_kernel<<<S, 256, 0, stream>>>(h, hn, n2_w + i * 1024, n2_b + i * 1024, 2);
        // q = hn @ cq_w
        bgemm_kernel<<<dim3(8, gy), 256, 0, stream>>>(hn, 1024, wt_cq, 1024, q_buf, nullptr, 1024,
                                                      S, 1024, 1024, cq_b + i * 1024, 0);
        // kv = cond @ ckv_w
        bgemm_kernel<<<dim3(16, 8), 256, 0, stream>>>(condb, 1024, wt_ckv, 1024, kv, nullptr, 2048,
                                                      1024, 2048, 1024, ckv_b + i * 2048, 0);
        // cross attention -> E
        attn_kernel<<<dim3(aqx, 16), 256, 0, stream>>>(q_buf, 1024, kv, 2048, kv + 1024, 2048, E, 1024, S, 1024);
        // co proj
        bgemm_kernel<<<dim3(8, gy), 256, 0, stream>>>(E, 1024, wt_co, 1024, F, nullptr, 1024,
                                                      S, 1024, 1024, co_b + i * 1024, 0);
        resid_kernel<<<S, 256, 0, stream>>>(h, F, nullptr, S * 256);

        // hn = ln(h)*(1+sc2)+sh2
        ln_kernel<<<S, 256, 0, stream>>>(h, hn, modb + 4 * 1024, modb + 3 * 1024, 1);
        // ff1 = gelu(hn @ mlp_w1 + b1)  (bf16 out)
        bgemm_kernel<<<dim3(32, gy), 256, 0, stream>>>(hn, 1024, wt_m1, 1024, nullptr, ff1, 4096,
                                                       S, 4096, 1024, mlp_b1 + i * 4096, 1);
        // ff2 = ff1 @ mlp_w2 + b2
        bgemm_kernel<<<dim3(8, gy), 256, 0, stream>>>(ff1, 4096, wt_m2, 4096, F, nullptr, 1024,
                                                      S, 1024, 4096, mlp_b2 + i * 1024, 0);
        resid_kernel<<<S, 256, 0, stream>>>(h, F, modb + 5 * 1024, S * 256);
    }
    // final LN + out proj + transpose
    ln_kernel<<<S, 256, 0, stream>>>(h, hn, nullptr, nullptr, 0);
    out_kernel<<<128, 256, 0, stream>>>(hn, out_w, out_b, (float*)d_out);
}